// Round 1
// baseline (567.425 us; speedup 1.0000x reference)
//
#include <hip/hip_runtime.h>
#include <hip/hip_bf16.h>

#define N_NODES 50000
#define F_IN    602
#define H_DIM   32
#define C_OUT   41
#define E_EDGES 800000
#define BN_EPS  1e-5f

// ---------------------------------------------------------------------------
// K1: p = x @ W1a  (N x 602 x 32), z = p + b1a
// 128 rows/block, K chunks of 32 staged in LDS, 4x4 microtile, float4 over k.
// LDS pad 36 floats/row; thread rows rgg+32i, cols cg+8j -> conflict-free b128.
// ---------------------------------------------------------------------------
__global__ __launch_bounds__(256) void k_gemm_in(
    const float* __restrict__ x, const float* __restrict__ W,
    const float* __restrict__ b, float* __restrict__ p, float* __restrict__ z) {
  __shared__ float xs[128 * 36];
  __shared__ float ws[32 * 36];   // W^T chunk: [c][k]
  const int tid = threadIdx.x;
  const int cg = tid & 7;         // col group: cols cg + 8j
  const int rgg = tid >> 3;       // row group: rows rgg + 32i
  const int r0 = blockIdx.x * 128;

  float acc[4][4] = {};

  for (int k0 = 0; k0 < F_IN; k0 += 32) {
    const int kc = min(32, F_IN - k0);
    // stage x tile [128][32] as float2 (x rows are 8B aligned: 602 % 2 == 0)
    for (int i = 0; i < 8; i++) {
      int f = tid + 256 * i;            // 0..2047
      int r = f >> 4;
      int kh = (f & 15) << 1;
      float2 v = {0.f, 0.f};
      int gr = r0 + r;
      if (gr < N_NODES) {
        int k = k0 + kh;
        if (k + 2 <= F_IN) v = *(const float2*)(x + (size_t)gr * F_IN + k);
        else if (k < F_IN) v.x = x[(size_t)gr * F_IN + k];
      }
      *(float2*)&xs[r * 36 + kh] = v;
    }
    // stage W^T chunk [32 cols][32 k]
    for (int i = 0; i < 4; i++) {
      int f = tid + 256 * i;            // 0..1023
      int k = f >> 5, c = f & 31;
      ws[c * 36 + k] = (k < kc) ? W[(size_t)(k0 + k) * H_DIM + c] : 0.f;
    }
    __syncthreads();
    #pragma unroll
    for (int kq = 0; kq < 8; kq++) {
      float4 xv[4], wv[4];
      #pragma unroll
      for (int i = 0; i < 4; i++) xv[i] = *(float4*)&xs[(rgg + 32 * i) * 36 + kq * 4];
      #pragma unroll
      for (int j = 0; j < 4; j++) wv[j] = *(float4*)&ws[(cg + 8 * j) * 36 + kq * 4];
      #pragma unroll
      for (int i = 0; i < 4; i++)
        #pragma unroll
        for (int j = 0; j < 4; j++)
          acc[i][j] += xv[i].x * wv[j].x + xv[i].y * wv[j].y +
                       xv[i].z * wv[j].z + xv[i].w * wv[j].w;
    }
    __syncthreads();
  }

  #pragma unroll
  for (int i = 0; i < 4; i++) {
    int gr = r0 + rgg + 32 * i;
    if (gr < N_NODES) {
      #pragma unroll
      for (int j = 0; j < 4; j++) {
        int c = cg + 8 * j;
        float v = acc[i][j];
        p[(size_t)gr * H_DIM + c] = v;
        z[(size_t)gr * H_DIM + c] = v + b[c];
      }
    }
  }
}

// ---------------------------------------------------------------------------
// K2: edge scatter: z[row[e]][c] += p[col[e]][c]   (32 lanes per edge)
// ---------------------------------------------------------------------------
__global__ __launch_bounds__(256) void k_scatter(
    const int* __restrict__ row, const int* __restrict__ col,
    const float* __restrict__ p, float* __restrict__ z) {
  long long t = (long long)blockIdx.x * 256 + threadIdx.x;
  int e = (int)(t >> 5);
  int c = (int)(t & 31);
  if (e < E_EDGES) {
    int s = col[e], d = row[e];
    atomicAdd(&z[(size_t)d * H_DIM + c], p[(size_t)s * H_DIM + c]);
  }
}

// ---------------------------------------------------------------------------
// K3: hpre = relu(z) @ W + b  (N x 32 x 32), fused BN partial sums
// stats: [0..31]=sum, [32..63]=sumsq (pre-zeroed)
// ---------------------------------------------------------------------------
__global__ __launch_bounds__(256) void k_mlp_stats(
    const float* __restrict__ z, const float* __restrict__ W,
    const float* __restrict__ b, float* __restrict__ hpre,
    float* __restrict__ stats) {
  __shared__ float as_[64 * 36];
  __shared__ float ws[32 * 36];
  __shared__ float red[512];
  const int tid = threadIdx.x;
  for (int i = tid; i < 1024; i += 256) {
    int k = i >> 5, c = i & 31;
    ws[c * 36 + k] = W[(size_t)k * H_DIM + c];
  }
  const int r0 = blockIdx.x * 64;
  for (int i = tid; i < 2048; i += 256) {
    int r = i >> 5, c = i & 31;
    int gr = r0 + r;
    float v = (gr < N_NODES) ? z[(size_t)gr * H_DIM + c] : 0.f;
    as_[r * 36 + c] = fmaxf(v, 0.f);
  }
  __syncthreads();
  const int c = tid & 31, rg = tid >> 5;
  float4 wc[8];
  #pragma unroll
  for (int q = 0; q < 8; q++) wc[q] = *(float4*)&ws[c * 36 + q * 4];
  const float bc = b[c];
  float lsum = 0.f, lsq = 0.f;
  #pragma unroll
  for (int i = 0; i < 8; i++) {
    int r = rg * 8 + i;
    float a = bc;
    #pragma unroll
    for (int q = 0; q < 8; q++) {
      float4 h4 = *(float4*)&as_[r * 36 + q * 4];
      a += h4.x * wc[q].x + h4.y * wc[q].y + h4.z * wc[q].z + h4.w * wc[q].w;
    }
    int gr = r0 + r;
    if (gr < N_NODES) {
      hpre[(size_t)gr * H_DIM + c] = a;
      lsum += a; lsq += a * a;
    }
  }
  __syncthreads();
  red[tid] = lsum; red[256 + tid] = lsq;
  __syncthreads();
  if (tid < 32) {
    float s = 0.f, q = 0.f;
    #pragma unroll
    for (int g = 0; g < 8; g++) { s += red[g * 32 + tid]; q += red[256 + g * 32 + tid]; }
    atomicAdd(&stats[tid], s);
    atomicAdd(&stats[32 + tid], q);
  }
}

// ---------------------------------------------------------------------------
// K4: BN finalize -> scale/shift per column
// ---------------------------------------------------------------------------
__global__ void k_bnfin(const float* __restrict__ stats, const float* __restrict__ g,
                        const float* __restrict__ be, float* __restrict__ ss) {
  int c = threadIdx.x;
  if (c < H_DIM) {
    float m = stats[c] / (float)N_NODES;
    float v = stats[32 + c] / (float)N_NODES - m * m;
    float sc = g[c] * rsqrtf(v + BN_EPS);
    ss[c] = sc;
    ss[32 + c] = be[c] - m * sc;
  }
}

// ---------------------------------------------------------------------------
// K5: p = (hpre*scale+shift) @ W  (N x 32 x 32), z = p + bz
// ---------------------------------------------------------------------------
__global__ __launch_bounds__(256) void k_gemm32_affine(
    const float* __restrict__ hpre, const float* __restrict__ ss,
    const float* __restrict__ W, const float* __restrict__ bz,
    float* __restrict__ p, float* __restrict__ z) {
  __shared__ float hs[64 * 36];
  __shared__ float ws[32 * 36];
  const int tid = threadIdx.x;
  for (int i = tid; i < 1024; i += 256) {
    int k = i >> 5, c = i & 31;
    ws[c * 36 + k] = W[(size_t)k * H_DIM + c];
  }
  const int r0 = blockIdx.x * 64;
  for (int i = tid; i < 2048; i += 256) {
    int r = i >> 5, c = i & 31;
    int gr = r0 + r;
    float v = (gr < N_NODES) ? hpre[(size_t)gr * H_DIM + c] * ss[c] + ss[32 + c] : 0.f;
    hs[r * 36 + c] = v;
  }
  __syncthreads();
  const int c = tid & 31, rg = tid >> 5;
  float4 wc[8];
  #pragma unroll
  for (int q = 0; q < 8; q++) wc[q] = *(float4*)&ws[c * 36 + q * 4];
  const float bzc = bz[c];
  #pragma unroll
  for (int i = 0; i < 8; i++) {
    int r = rg * 8 + i;
    float a = 0.f;
    #pragma unroll
    for (int q = 0; q < 8; q++) {
      float4 h4 = *(float4*)&hs[r * 36 + q * 4];
      a += h4.x * wc[q].x + h4.y * wc[q].y + h4.z * wc[q].z + h4.w * wc[q].w;
    }
    int gr = r0 + r;
    if (gr < N_NODES) {
      p[(size_t)gr * H_DIM + c] = a;
      z[(size_t)gr * H_DIM + c] = a + bzc;
    }
  }
}

// ---------------------------------------------------------------------------
// K6: heads: out = relu((hpre*sc+sh)@Wf1 + bf1) @ Wf2 + bf2
// ---------------------------------------------------------------------------
__global__ __launch_bounds__(256) void k_heads(
    const float* __restrict__ hpre, const float* __restrict__ ss,
    const float* __restrict__ W1, const float* __restrict__ b1,
    const float* __restrict__ W2, const float* __restrict__ b2,
    float* __restrict__ out) {
  __shared__ float hs[64 * 36];
  __shared__ float fs[64 * 36];
  __shared__ float w1[32 * 36];
  __shared__ float w2[41 * 36];
  const int tid = threadIdx.x;
  for (int i = tid; i < 1024; i += 256) {
    int k = i >> 5, c = i & 31;
    w1[c * 36 + k] = W1[(size_t)k * H_DIM + c];
  }
  for (int i = tid; i < 41 * 32; i += 256) {
    int j = i >> 5, k = i & 31;
    w2[j * 36 + k] = W2[(size_t)k * C_OUT + j];
  }
  const int r0 = blockIdx.x * 64;
  for (int i = tid; i < 2048; i += 256) {
    int r = i >> 5, c = i & 31;
    int gr = r0 + r;
    hs[r * 36 + c] = (gr < N_NODES) ? hpre[(size_t)gr * H_DIM + c] * ss[c] + ss[32 + c] : 0.f;
  }
  __syncthreads();
  {
    const int c = tid & 31, rg = tid >> 5;
    float4 wc[8];
    #pragma unroll
    for (int q = 0; q < 8; q++) wc[q] = *(float4*)&w1[c * 36 + q * 4];
    const float bc = b1[c];
    #pragma unroll
    for (int i = 0; i < 8; i++) {
      int r = rg * 8 + i;
      float a = bc;
      #pragma unroll
      for (int q = 0; q < 8; q++) {
        float4 h4 = *(float4*)&hs[r * 36 + q * 4];
        a += h4.x * wc[q].x + h4.y * wc[q].y + h4.z * wc[q].z + h4.w * wc[q].w;
      }
      fs[r * 36 + c] = fmaxf(a, 0.f);
    }
  }
  __syncthreads();
  for (int idx = tid; idx < 64 * C_OUT; idx += 256) {
    int r = idx / C_OUT, j = idx - r * C_OUT;
    int gr = r0 + r;
    if (gr < N_NODES) {
      float a = b2[j];
      #pragma unroll
      for (int q = 0; q < 8; q++) {
        float4 f4 = *(float4*)&fs[r * 36 + q * 4];
        float4 w4 = *(float4*)&w2[j * 36 + q * 4];
        a += f4.x * w4.x + f4.y * w4.y + f4.z * w4.z + f4.w * w4.w;
      }
      out[(size_t)gr * C_OUT + j] = a;
    }
  }
}

// ---------------------------------------------------------------------------
extern "C" void kernel_launch(void* const* d_in, const int* in_sizes, int n_in,
                              void* d_out, int out_size, void* d_ws, size_t ws_size,
                              hipStream_t stream) {
  const float* x   = (const float*)d_in[0];
  const int* row   = (const int*)d_in[1];
  const int* col   = (const int*)d_in[2];
  const float* W1a = (const float*)d_in[3];
  const float* b1a = (const float*)d_in[4];
  const float* W1b = (const float*)d_in[5];
  const float* b1b = (const float*)d_in[6];
  const float* g1  = (const float*)d_in[7];
  const float* be1 = (const float*)d_in[8];
  const float* W2a = (const float*)d_in[9];
  const float* b2a = (const float*)d_in[10];
  const float* W2b = (const float*)d_in[11];
  const float* b2b = (const float*)d_in[12];
  const float* g2  = (const float*)d_in[13];
  const float* be2 = (const float*)d_in[14];
  const float* Wf1 = (const float*)d_in[15];
  const float* bf1 = (const float*)d_in[16];
  const float* Wf2 = (const float*)d_in[17];
  const float* bf2 = (const float*)d_in[18];
  float* out = (float*)d_out;

  float* ws = (float*)d_ws;
  float* pA    = ws;                               // N*32
  float* zB    = ws + (size_t)N_NODES * H_DIM;     // N*32
  float* hC    = ws + (size_t)2 * N_NODES * H_DIM; // N*32
  float* stats = ws + (size_t)3 * N_NODES * H_DIM; // 256 floats:
  // [0..63] sums1, [64..127] ss1, [128..191] sums2, [192..255] ss2

  hipMemsetAsync(stats, 0, 256 * sizeof(float), stream);

  const int gBig   = (N_NODES + 127) / 128;        // 391
  const int g64    = (N_NODES + 63) / 64;          // 782
  const int gScat  = (E_EDGES * 32 + 255) / 256;   // 100000

  // conv1
  k_gemm_in<<<gBig, 256, 0, stream>>>(x, W1a, b1a, pA, zB);
  k_scatter<<<gScat, 256, 0, stream>>>(row, col, pA, zB);
  k_mlp_stats<<<g64, 256, 0, stream>>>(zB, W1b, b1b, hC, stats);
  k_bnfin<<<1, 64, 0, stream>>>(stats, g1, be1, stats + 64);
  // conv2
  k_gemm32_affine<<<g64, 256, 0, stream>>>(hC, stats + 64, W2a, b2a, pA, zB);
  k_scatter<<<gScat, 256, 0, stream>>>(row, col, pA, zB);
  k_mlp_stats<<<g64, 256, 0, stream>>>(zB, W2b, b2b, hC, stats + 128);
  k_bnfin<<<1, 64, 0, stream>>>(stats + 128, g2, be2, stats + 192);
  // heads
  k_heads<<<g64, 256, 0, stream>>>(hC, stats + 192, Wf1, bf1, Wf2, bf2, out);
}